// Round 4
// baseline (1132.948 us; speedup 1.0000x reference)
//
#include <hip/hip_runtime.h>
#include <stdint.h>

#define LAYERS 4
#define BB 16
#define TT 512
#define CC 1024
#define HH 16
#define DD 64
#define VV 32000
#define MM (BB*TT)   // 8192 rows

typedef __attribute__((ext_vector_type(8))) short bf16x8;
typedef __attribute__((ext_vector_type(4))) float f32x4;
typedef __attribute__((ext_vector_type(16))) float f32x16;

__device__ __forceinline__ unsigned short f2b(float f) {
  union { float f; unsigned int u; } v; v.f = f;
  unsigned int r = v.u + 0x7FFFu + ((v.u >> 16) & 1u);
  return (unsigned short)(r >> 16);
}
__device__ __forceinline__ float blo(unsigned int u) {
  union { unsigned int x; float f; } v; v.x = u << 16; return v.f;
}
__device__ __forceinline__ float bhi(unsigned int u) {
  union { unsigned int x; float f; } v; v.x = u & 0xFFFF0000u; return v.f;
}
__device__ __forceinline__ uint32_t pkbf(float lo, float hi) {
  uint32_t d; asm("v_cvt_pk_bf16_f32 %0, %1, %2" : "=v"(d) : "v"(lo), "v"(hi)); return d;
}
__device__ __forceinline__ float ex2(float x) {
  float r; asm("v_exp_f32 %0, %1" : "=v"(r) : "v"(x)); return r;
}
__device__ __forceinline__ void gload16(const unsigned short* g, const unsigned short* lds) {
  __builtin_amdgcn_global_load_lds((const __attribute__((address_space(1))) void*)g,
                                   (__attribute__((address_space(3))) void*)lds, 16, 0, 0);
}

// ---------------- weight fp32 -> bf16 ----------------
__global__ __launch_bounds__(256) void cvt_kernel(const float* __restrict__ src,
                                                  unsigned short* __restrict__ dst, int n4) {
  int i = blockIdx.x * 256 + threadIdx.x;
  if (i >= n4) return;
  float4 v = ((const float4*)src)[i];
  ushort4 o; o.x = f2b(v.x); o.y = f2b(v.y); o.z = f2b(v.z); o.w = f2b(v.w);
  ((ushort4*)dst)[i] = o;
}

// ---------------- embedding: x = emb[Xm] + pos ----------------
__global__ __launch_bounds__(256) void embed_kernel(const int* __restrict__ X, const int* __restrict__ S,
    const float* __restrict__ emb, const float* __restrict__ pos,
    float* __restrict__ x, unsigned short* __restrict__ xb) {
  int bt = blockIdx.x; int tid = threadIdx.x;
  int t = bt & (TT - 1);
  int tok = S[bt] ? X[bt] : VV;
  float4 e = ((const float4*)(emb + (size_t)tok * CC))[tid];
  float4 p = ((const float4*)(pos + (size_t)t * CC))[tid];
  float4 r; r.x = e.x + p.x; r.y = e.y + p.y; r.z = e.z + p.z; r.w = e.w + p.w;
  ((float4*)(x + (size_t)bt * CC))[tid] = r;
  ushort4 ub; ub.x = f2b(r.x); ub.y = f2b(r.y); ub.z = f2b(r.z); ub.w = f2b(r.w);
  ((ushort4*)(xb + (size_t)bt * CC))[tid] = ub;
}

// ---------------- GEMM v3: 256x256 tile, 8 waves (2Mx4N), per-wave 128x64 ----------------
// K = 1024 fixed (NT=16). 4 phases per K-tile: (Mq,kk) in {(0,0),(1,0),(0,1),(1,1)}.
// LDS 128KB: A regions [2 parity][2 kk][256][32] bf16, B same. Conflict-free layout (64B rows).
// Staging: stage slot = first phase after region's last read (1-barrier separation).
//   P1(t): A-kk1(t+1)  P2(t): B-kk1(t+1)  P3(t): A-kk0(t+2)  P4(t): B-kk0(t+2)
// Gates: vmcnt(8) before post-MFMA barrier of P2 and P4 (steady); tail 8,4 then 0.
template<int EPI>
__global__ __launch_bounds__(512, 2) void gemm3_kernel(
    const unsigned short* __restrict__ A,   // M x 1024 bf16
    const unsigned short* __restrict__ W,   // N x 1024 bf16
    float* __restrict__ xres,
    unsigned short* __restrict__ outb,
    const float* __restrict__ bias,
    int N, int nbx) {
  extern __shared__ unsigned short lds[];   // A: 4*8192 shorts, B: 4*8192 shorts
  const int K = 1024;
  const int tid = threadIdx.x;
  const int wv = tid >> 6, ln = tid & 63;
  const int g = ln >> 4, rr = ln & 15;
  const int wm = wv >> 2, wn = wv & 3;

  const int nwg = gridDim.x;
  const int bid = blockIdx.x;
  const int swz = (bid & 7) * (nwg >> 3) + (bid >> 3);
  const int by = swz / nbx, bx = swz - by * nbx;
  const int brow = by * 256, bcol = bx * 256;

  // staging source pointers (2 loads per region: rows tid>>2 and 128+tid>>2)
  const int srow = tid >> 2;
  const int scol = (tid & 3) * 8;
  const unsigned short* aP0 = A + (size_t)(brow + srow) * K + scol;
  const unsigned short* aP1 = aP0 + (size_t)128 * K;
  const unsigned short* bP0 = W + (size_t)(bcol + srow) * K + scol;
  const unsigned short* bP1 = bP0 + (size_t)128 * K;

  auto stA = [&](int t, int kk) {
    unsigned short* d = lds + ((((t & 1) << 1) | kk) * 8192) + wv * 512;
    int ko = t * 64 + kk * 32;
    gload16(aP0 + ko, d);
    gload16(aP1 + ko, d + 4096);
  };
  auto stB = [&](int t, int kk) {
    unsigned short* d = lds + 32768 + ((((t & 1) << 1) | kk) * 8192) + wv * 512;
    int ko = t * 64 + kk * 32;
    gload16(bP0 + ko, d);
    gload16(bP1 + ko, d + 4096);
  };
  auto g8 = [&] { asm volatile("s_waitcnt vmcnt(8)" ::: "memory"); };
  auto g4 = [&] { asm volatile("s_waitcnt vmcnt(4)" ::: "memory"); };
  auto g0 = [&] { asm volatile("s_waitcnt vmcnt(0)" ::: "memory"); };
  auto gn = [&] {};

  f32x4 acc[8][4];
  #pragma unroll
  for (int i = 0; i < 8; ++i)
    #pragma unroll
    for (int j = 0; j < 4; ++j)
      acc[i][j] = (f32x4){0.f, 0.f, 0.f, 0.f};

  // prologue: regions whose stage slots precede t=0
  stA(0, 0); stB(0, 0); stA(0, 1); stB(0, 1); stA(1, 0); stB(1, 0);   // 12 loads
  g8();   // kk0(0) A+B landed
  __builtin_amdgcn_s_barrier();

#define PH(MQ, KK, STG, GT) { \
    const unsigned short* Ar = lds + (((t & 1) << 1) | KK) * 8192; \
    const unsigned short* Br = lds + 32768 + (((t & 1) << 1) | KK) * 8192; \
    bf16x8 av[4], bv[4]; \
    _Pragma("unroll") \
    for (int ii = 0; ii < 4; ++ii) \
      av[ii] = *(const bf16x8*)(Ar + (wm * 128 + MQ * 64 + ii * 16 + rr) * 32 + g * 8); \
    _Pragma("unroll") \
    for (int j = 0; j < 4; ++j) \
      bv[j] = *(const bf16x8*)(Br + (wn * 64 + j * 16 + rr) * 32 + g * 8); \
    STG; \
    __builtin_amdgcn_s_barrier(); \
    __builtin_amdgcn_s_setprio(1); \
    _Pragma("unroll") \
    for (int ii = 0; ii < 4; ++ii) \
      _Pragma("unroll") \
      for (int j = 0; j < 4; ++j) \
        acc[MQ * 4 + ii][j] = __builtin_amdgcn_mfma_f32_16x16x32_bf16(av[ii], bv[j], acc[MQ * 4 + ii][j], 0, 0, 0); \
    __builtin_amdgcn_s_setprio(0); \
    GT; \
    __builtin_amdgcn_s_barrier(); \
  }

  for (int t = 0; t < 14; ++t) {
    PH(0, 0, stA(t + 1, 1), gn())
    PH(1, 0, stB(t + 1, 1), g8())
    PH(0, 1, stA(t + 2, 0), gn())
    PH(1, 1, stB(t + 2, 0), g8())
  }
  {
    int t = 14;
    PH(0, 0, stA(15, 1), gn())
    PH(1, 0, stB(15, 1), g8())
    PH(0, 1, gn(), gn())
    PH(1, 1, gn(), g4())
  }
  {
    int t = 15;
    PH(0, 0, gn(), gn())
    PH(1, 0, gn(), g0())
    PH(0, 1, gn(), gn())
    PH(1, 1, gn(), gn())
  }
#undef PH

  // epilogue: D row = (ln>>4)*4 + q, col = ln&15
  #pragma unroll
  for (int mq = 0; mq < 2; ++mq) {
    #pragma unroll
    for (int ii = 0; ii < 4; ++ii) {
      #pragma unroll
      for (int j = 0; j < 4; ++j) {
        #pragma unroll
        for (int q = 0; q < 4; ++q) {
          int rowg = brow + wm * 128 + mq * 64 + ii * 16 + g * 4 + q;
          int colg = bcol + wn * 64 + j * 16 + rr;
          size_t off = (size_t)rowg * N + colg;
          float vacc = acc[mq * 4 + ii][j][q];
          if (EPI == 0) {
            outb[off] = f2b(vacc);
          } else if (EPI == 1) {
            float nx = xres[off] + vacc;
            xres[off] = nx; outb[off] = f2b(nx);
          } else if (EPI == 2) {
            float hv = vacc + bias[colg];
            hv = hv > 0.f ? hv : 0.f;
            outb[off] = f2b(hv);
          } else {
            float nx = xres[off] + vacc + bias[colg];
            xres[off] = nx; outb[off] = f2b(nx);
          }
        }
      }
    }
  }
}

// ---------------- MFMA flash attention (unchanged from R2) ----------------
template<int E>
__device__ __forceinline__ bf16x8 buildP(const f32x16& p) {
  uint32_t a = pkbf(p[E + 0], p[E + 1]);
  uint32_t b = pkbf(p[E + 4], p[E + 5]);
  uint32_t c = pkbf(p[E + 2], p[E + 3]);
  uint32_t d = pkbf(p[E + 6], p[E + 7]);
  asm("v_permlane32_swap_b32 %0, %1" : "+v"(a), "+v"(b));
  asm("v_permlane32_swap_b32 %0, %1" : "+v"(c), "+v"(d));
  union { uint32_t u[4]; bf16x8 v; } r;
  r.u[0] = a; r.u[1] = c; r.u[2] = b; r.u[3] = d;
  return r.v;
}

__global__ __launch_bounds__(256) void attn_kernel(const unsigned short* __restrict__ qkv,
                                                   unsigned short* __restrict__ ob) {
  __shared__ unsigned short Kl[64 * 64];
  __shared__ unsigned short Vt[64 * 64];
  const int tid = threadIdx.x;
  const int wv = tid >> 6, ln = tid & 63;
  const int lq = ln & 31, hi = ln >> 5;
  const int qt = blockIdx.x >> 8, bh = blockIdx.x & 255;
  const int b = bh >> 4, h = bh & 15;
  const int qrow = qt * 128 + wv * 32 + lq;
  const size_t rowQ = (size_t)(b * TT + qrow) * 3072 + h * 64;

  const float cs = 0.125f * 1.44269504f;
  bf16x8 qf[4];
  #pragma unroll
  for (int t = 0; t < 4; ++t) {
    uint4 u = *(const uint4*)(qkv + rowQ + t * 16 + hi * 8);
    uint32_t w[4] = {u.x, u.y, u.z, u.w};
    union { uint32_t u4[4]; bf16x8 v; } cv;
    #pragma unroll
    for (int j = 0; j < 4; ++j) cv.u4[j] = pkbf(blo(w[j]) * cs, bhi(w[j]) * cs);
    qf[t] = cv.v;
  }

  f32x16 o0 = {}, o1 = {};
  float mrun = -3.0e38f, lsum = 0.f;

  for (int kv0 = 0; kv0 < TT; kv0 += 64) {
    if (kv0) __syncthreads();
    #pragma unroll
    for (int r = 0; r < 2; ++r) {
      int ch = r * 256 + tid;
      int k = ch >> 3, cc = ch & 7;
      int sg = (k & 7) ^ (k >> 3);
      const unsigned short* gs = qkv + (size_t)(b * TT + kv0 + k) * 3072 + 1024 + h * 64 + ((cc ^ sg) << 3);
      gload16(gs, Kl + (size_t)(r * 256 + wv * 64) * 8);
    }
    {
      int cc = tid & 7, kp = tid >> 3;
      int k = kp * 2;
      const unsigned short* gv = qkv + (size_t)(b * TT + kv0 + k) * 3072 + 2048 + h * 64 + cc * 8;
      uint4 g1 = *(const uint4*)gv;
      uint4 g2 = *(const uint4*)(gv + 3072);
      uint32_t w1[4] = {g1.x, g1.y, g1.z, g1.w}, w2[4] = {g2.x, g2.y, g2.z, g2.w};
      #pragma unroll
      for (int j = 0; j < 8; ++j) {
        int d = cc * 8 + j;
        uint32_t dw = (j & 1) ? ((w1[j >> 1] >> 16) | (w2[j >> 1] & 0xFFFF0000u))
                              : ((w1[j >> 1] & 0xFFFFu) | (w2[j >> 1] << 16));
        int sg = (d & 7) ^ (d >> 3);
        *(uint32_t*)(Vt + d * 64 + (k ^ (sg << 3))) = dw;
      }
    }
    __syncthreads();

    f32x16 s0 = {}, s1 = {};
    #pragma unroll
    for (int t = 0; t < 4; ++t) {
      int r0 = lq, r1 = 32 + lq;
      bf16x8 a0 = *(const bf16x8*)(Kl + r0 * 64 + ((((t << 1) | hi) ^ ((r0 & 7) ^ (r0 >> 3))) << 3));
      bf16x8 a1 = *(const bf16x8*)(Kl + r1 * 64 + ((((t << 1) | hi) ^ ((r1 & 7) ^ (r1 >> 3))) << 3));
      s0 = __builtin_amdgcn_mfma_f32_32x32x16_bf16(a0, qf[t], s0, 0, 0, 0);
      s1 = __builtin_amdgcn_mfma_f32_32x32x16_bf16(a1, qf[t], s1, 0, 0, 0);
    }

    float mx = s0[0];
    #pragma unroll
    for (int r = 1; r < 16; ++r) mx = fmaxf(mx, s0[r]);
    #pragma unroll
    for (int r = 0; r < 16; ++r) mx = fmaxf(mx, s1[r]);
    mx = fmaxf(mx, __shfl_xor(mx, 32));
    float mnew = fmaxf(mrun, mx);
    float cf = ex2(mrun - mnew);
    mrun = mnew;
    lsum *= cf;
    #pragma unroll
    for (int r = 0; r < 16; ++r) { o0[r] *= cf; o1[r] *= cf; }
    #pragma unroll
    for (int r = 0; r < 16; ++r) {
      s0[r] = ex2(s0[r] - mnew);
      s1[r] = ex2(s1[r] - mnew);
      lsum += s0[r] + s1[r];
    }

    bf16x8 pf0 = buildP<0>(s0);
    bf16x8 pf1 = buildP<8>(s0);
    bf16x8 pf2 = buildP<0>(s1);
    bf16x8 pf3 = buildP<8>(s1);

    #pragma unroll
    for (int t = 0; t < 4; ++t) {
      bf16x8 pf = (t == 0) ? pf0 : (t == 1) ? pf1 : (t == 2) ? pf2 : pf3;
      int d0 = lq, d1 = 32 + lq;
      bf16x8 v0 = *(const bf16x8*)(Vt + d0 * 64 + ((((t << 1) | hi) ^ ((d0 & 7) ^ (d0 >> 3))) << 3));
      bf16x8 v1 = *(const bf16x8*)(Vt + d1 * 64 + ((((t << 1) | hi) ^ ((d1 & 7) ^ (d1 >> 3))) << 3));
      o0 = __builtin_amdgcn_mfma_f32_32x32x16_bf16(v0, pf, o0, 0, 0, 0);
      o1 = __builtin_amdgcn_mfma_f32_32x32x16_bf16(v1, pf, o1, 0, 0, 0);
    }
  }

  lsum += __shfl_xor(lsum, 32);
  float inv = 1.f / lsum;
  size_t orow = (size_t)(b * TT + qrow) * CC + h * 64;
  #pragma unroll
  for (int md = 0; md < 2; ++md) {
    #pragma unroll
    for (int rq = 0; rq < 4; ++rq) {
      int d0 = md * 32 + rq * 8 + hi * 4;
      float e0 = (md ? o1[rq * 4 + 0] : o0[rq * 4 + 0]) * inv;
      float e1 = (md ? o1[rq * 4 + 1] : o0[rq * 4 + 1]) * inv;
      float e2 = (md ? o1[rq * 4 + 2] : o0[rq * 4 + 2]) * inv;
      float e3 = (md ? o1[rq * 4 + 3] : o0[rq * 4 + 3]) * inv;
      uint2 st; st.x = pkbf(e0, e1); st.y = pkbf(e2, e3);
      *(uint2*)(ob + orow + d0) = st;
    }
  }
}

// ---------------- final: out[b,c] = sum_t x[b,t,c] * I[b,t] ----------------
__global__ __launch_bounds__(256) void final_kernel(const float* __restrict__ x,
                                                    const float* __restrict__ I,
                                                    float* __restrict__ out) {
  int b = blockIdx.x >> 2;
  int c = ((blockIdx.x & 3) << 8) + threadIdx.x;
  float acc = 0.f;
  const float* xp = x + (size_t)b * TT * CC + c;
  const float* Ip = I + (size_t)b * TT;
  for (int t = 0; t < TT; ++t) acc = fmaf(xp[(size_t)t * CC], Ip[t], acc);
  out[b * CC + c] = acc;
}

extern "C" void kernel_launch(void* const* d_in, const int* in_sizes, int n_in,
                              void* d_out, int out_size, void* d_ws, size_t ws_size,
                              hipStream_t stream) {
  const int*   X      = (const int*)d_in[0];
  const float* I      = (const float*)d_in[1];
  const int*   S      = (const int*)d_in[2];
  const float* emb    = (const float*)d_in[3];
  const float* pos    = (const float*)d_in[4];
  const float* qkv_w  = (const float*)d_in[5];
  const float* out_w  = (const float*)d_in[6];
  const float* ffn_w1 = (const float*)d_in[7];
  const float* ffn_b1 = (const float*)d_in[8];
  const float* ffn_w2 = (const float*)d_in[9];
  const float* ffn_b2 = (const float*)d_in[10];
  float* out = (float*)d_out;

  char* ws = (char*)d_ws;
  size_t off = 0;
  auto walloc = [&](size_t bytes) { char* p = ws + off; off += (bytes + 255) & ~(size_t)255; return p; };
  unsigned short* wqkv = (unsigned short*)walloc((size_t)LAYERS * 3 * CC * CC * 2);
  unsigned short* wo   = (unsigned short*)walloc((size_t)LAYERS * CC * CC * 2);
  unsigned short* w1   = (unsigned short*)walloc((size_t)LAYERS * CC * CC * 2);
  unsigned short* w2   = (unsigned short*)walloc((size_t)LAYERS * CC * CC * 2);
  float*          x    = (float*)walloc((size_t)MM * CC * 4);
  unsigned short* xb   = (unsigned short*)walloc((size_t)MM * CC * 2);
  unsigned short* qkvb = (unsigned short*)walloc((size_t)MM * 3 * CC * 2);
  unsigned short* obuf = (unsigned short*)walloc((size_t)MM * CC * 2);
  unsigned short* hbuf = (unsigned short*)walloc((size_t)MM * CC * 2);
  if (off > ws_size) return;

  int n4;
  n4 = LAYERS * 3 * CC * CC / 4; cvt_kernel<<<(n4 + 255) / 256, 256, 0, stream>>>(qkv_w, wqkv, n4);
  n4 = LAYERS * CC * CC / 4;     cvt_kernel<<<(n4 + 255) / 256, 256, 0, stream>>>(out_w, wo, n4);
  n4 = LAYERS * CC * CC / 4;     cvt_kernel<<<(n4 + 255) / 256, 256, 0, stream>>>(ffn_w1, w1, n4);
  n4 = LAYERS * CC * CC / 4;     cvt_kernel<<<(n4 + 255) / 256, 256, 0, stream>>>(ffn_w2, w2, n4);

  embed_kernel<<<MM, 256, 0, stream>>>(X, S, emb, pos, x, xb);

  const size_t ldsB = 128 * 1024;
  for (int l = 0; l < LAYERS; ++l) {
    gemm3_kernel<0><<<(MM / 256) * (3 * CC / 256), 512, ldsB, stream>>>(
        xb, wqkv + (size_t)l * 3 * CC * CC, nullptr, qkvb, nullptr, 3 * CC, 3 * CC / 256);
    attn_kernel<<<4 * 256, 256, 0, stream>>>(qkvb, obuf);
    gemm3_kernel<1><<<(MM / 256) * (CC / 256), 512, ldsB, stream>>>(
        obuf, wo + (size_t)l * CC * CC, x, xb, nullptr, CC, CC / 256);
    gemm3_kernel<2><<<(MM / 256) * (CC / 256), 512, ldsB, stream>>>(
        xb, w1 + (size_t)l * CC * CC, nullptr, hbuf, ffn_b1 + l * CC, CC, CC / 256);
    gemm3_kernel<3><<<(MM / 256) * (CC / 256), 512, ldsB, stream>>>(
        hbuf, w2 + (size_t)l * CC * CC, x, xb, ffn_b2 + l * CC, CC, CC / 256);
  }

  final_kernel<<<BB * 4, 256, 0, stream>>>(x, I, out);
}

// Round 6
// 823.748 us; speedup vs baseline: 1.3754x; 1.3754x over previous
//
#include <hip/hip_runtime.h>
#include <stdint.h>

#define LAYERS 4
#define BB 16
#define TT 512
#define CC 1024
#define HH 16
#define DD 64
#define VV 32000
#define MM (BB*TT)   // 8192 rows

typedef __attribute__((ext_vector_type(8))) short bf16x8;
typedef __attribute__((ext_vector_type(4))) float f32x4;
typedef __attribute__((ext_vector_type(16))) float f32x16;

__device__ __forceinline__ unsigned short f2b(float f) {
  union { float f; unsigned int u; } v; v.f = f;
  unsigned int r = v.u + 0x7FFFu + ((v.u >> 16) & 1u);
  return (unsigned short)(r >> 16);
}
__device__ __forceinline__ float blo(unsigned int u) {
  union { unsigned int x; float f; } v; v.x = u << 16; return v.f;
}
__device__ __forceinline__ float bhi(unsigned int u) {
  union { unsigned int x; float f; } v; v.x = u & 0xFFFF0000u; return v.f;
}
__device__ __forceinline__ uint32_t pkbf(float lo, float hi) {
  uint32_t d; asm("v_cvt_pk_bf16_f32 %0, %1, %2" : "=v"(d) : "v"(lo), "v"(hi)); return d;
}
__device__ __forceinline__ float ex2(float x) {
  float r; asm("v_exp_f32 %0, %1" : "=v"(r) : "v"(x)); return r;
}
__device__ __forceinline__ void gload16(const unsigned short* g, const unsigned short* lds) {
  __builtin_amdgcn_global_load_lds((const __attribute__((address_space(1))) void*)g,
                                   (__attribute__((address_space(3))) void*)lds, 16, 0, 0);
}

// ---------------- weight fp32 -> bf16 ----------------
__global__ __launch_bounds__(256) void cvt_kernel(const float* __restrict__ src,
                                                  unsigned short* __restrict__ dst, int n4) {
  int i = blockIdx.x * 256 + threadIdx.x;
  if (i >= n4) return;
  float4 v = ((const float4*)src)[i];
  ushort4 o; o.x = f2b(v.x); o.y = f2b(v.y); o.z = f2b(v.z); o.w = f2b(v.w);
  ((ushort4*)dst)[i] = o;
}

// ---------------- embedding: x = emb[Xm] + pos ----------------
__global__ __launch_bounds__(256) void embed_kernel(const int* __restrict__ X, const int* __restrict__ S,
    const float* __restrict__ emb, const float* __restrict__ pos,
    float* __restrict__ x, unsigned short* __restrict__ xb) {
  int bt = blockIdx.x; int tid = threadIdx.x;
  int t = bt & (TT - 1);
  int tok = S[bt] ? X[bt] : VV;
  float4 e = ((const float4*)(emb + (size_t)tok * CC))[tid];
  float4 p = ((const float4*)(pos + (size_t)t * CC))[tid];
  float4 r; r.x = e.x + p.x; r.y = e.y + p.y; r.z = e.z + p.z; r.w = e.w + p.w;
  ((float4*)(x + (size_t)bt * CC))[tid] = r;
  ushort4 ub; ub.x = f2b(r.x); ub.y = f2b(r.y); ub.z = f2b(r.z); ub.w = f2b(r.w);
  ((ushort4*)(xb + (size_t)bt * CC))[tid] = ub;
}

// ---------------- GEMM v4: 256x128 tile, triple-buffer, counted gates (per-WAVE counts) ----------------
// K = 1024 fixed (NT=16). 8 waves (4M x 2N), per-wave 64x64.
// LDS 144KB: 3 buffers x (A[256][64] + B[128][64]) bf16, chunk-XOR swizzled (0 conflicts, R3-verified).
// Per-wave loads: 6 per stage. Depth-2 prefetch: at iter t issue stage(t+2);
// gate vmcnt(12) == "tile t landed; t+1/t+2 (12 loads) in flight". Tail: vmcnt(6) at t=14, vmcnt(0) at t=15.
// R5 bug: gates counted per-block (24/12) -> no-ops -> replay race. Fixed here.
template<int EPI>
__global__ __launch_bounds__(512, 1) void gemm4_kernel(
    const unsigned short* __restrict__ A,   // M x 1024 bf16
    const unsigned short* __restrict__ W,   // N x 1024 bf16
    float* __restrict__ xres,
    unsigned short* __restrict__ outb,
    const float* __restrict__ bias,
    int N, int nbx) {
  extern __shared__ unsigned short lds[];   // 3 x 24576 shorts
  const int K = 1024;
  const int tid = threadIdx.x;
  const int wv = tid >> 6, ln = tid & 63;
  const int g = ln >> 4, rr = ln & 15;
  const int wm = wv >> 1, wn = wv & 1;

  const int nwg = gridDim.x;
  const int bid = blockIdx.x;
  const int swz = (bid & 7) * (nwg >> 3) + (bid >> 3);
  const int by = swz / nbx, bx = swz - by * nbx;   // bx fast -> A rows L2-resident per XCD
  const int brow = by * 256, bcol = bx * 128;

  // staging source pointers (chunk column pre-XORed by row&7; G21 both-sides swizzle)
  const unsigned short* asrc[4];
  const unsigned short* bsrc[2];
  #pragma unroll
  for (int rd = 0; rd < 4; ++rd) {
    int ch = rd * 512 + tid;
    int row = ch >> 3, c = (ch & 7) ^ (row & 7);
    asrc[rd] = A + (size_t)(brow + row) * K + c * 8;
  }
  #pragma unroll
  for (int rd = 0; rd < 2; ++rd) {
    int ch = rd * 512 + tid;
    int row = ch >> 3, c = (ch & 7) ^ (row & 7);
    bsrc[rd] = W + (size_t)(bcol + row) * K + c * 8;
  }

  auto stage = [&](int tile, int buf) {
    unsigned short* Ad = lds + buf * 24576 + wv * 512;
    unsigned short* Bd = lds + buf * 24576 + 16384 + wv * 512;
    int ko = tile * 64;
    #pragma unroll
    for (int rd = 0; rd < 4; ++rd) gload16(asrc[rd] + ko, Ad + rd * 4096);
    #pragma unroll
    for (int rd = 0; rd < 2; ++rd) gload16(bsrc[rd] + ko, Bd + rd * 4096);
  };

  f32x4 acc[4][4];
  #pragma unroll
  for (int i = 0; i < 4; ++i)
    #pragma unroll
    for (int j = 0; j < 4; ++j)
      acc[i][j] = (f32x4){0.f, 0.f, 0.f, 0.f};

  stage(0, 0);
  stage(1, 1);

  int bufc = 0;
  for (int t = 0; t < 16; ++t) {
    int bufn = bufc + 2; if (bufn >= 3) bufn -= 3;
    if (t < 14) {
      stage(t + 2, bufn);
      asm volatile("s_waitcnt vmcnt(12)" ::: "memory");   // tile t landed (6/tile per wave)
    } else if (t == 14) {
      asm volatile("s_waitcnt vmcnt(6)" ::: "memory");    // tile 14 landed, 15 in flight
    } else {
      asm volatile("s_waitcnt vmcnt(0)" ::: "memory");    // tile 15 landed
    }
    __builtin_amdgcn_s_barrier();
    __builtin_amdgcn_sched_barrier(0);

    const unsigned short* Ab = lds + bufc * 24576;
    const unsigned short* Bb = Ab + 16384;
    bf16x8 av[2][4], bv[2][4];
    #pragma unroll
    for (int kk = 0; kk < 2; ++kk) {
      int chx = ((kk * 4 + g) ^ (rr & 7)) << 3;
      #pragma unroll
      for (int i = 0; i < 4; ++i) {
        av[kk][i] = *(const bf16x8*)(Ab + (wm * 64 + i * 16 + rr) * 64 + chx);
        bv[kk][i] = *(const bf16x8*)(Bb + (wn * 64 + i * 16 + rr) * 64 + chx);
      }
    }
    __builtin_amdgcn_s_setprio(1);
    #pragma unroll
    for (int kk = 0; kk < 2; ++kk)
      #pragma unroll
      for (int i = 0; i < 4; ++i)
        #pragma unroll
        for (int j = 0; j < 4; ++j)
          acc[i][j] = __builtin_amdgcn_mfma_f32_16x16x32_bf16(av[kk][i], bv[kk][j], acc[i][j], 0, 0, 0);
    __builtin_amdgcn_s_setprio(0);
    __builtin_amdgcn_sched_barrier(0);
    __builtin_amdgcn_s_barrier();
    bufc += 1; if (bufc == 3) bufc = 0;
  }

  // epilogue: D row = (ln>>4)*4 + q, col = ln&15
  #pragma unroll
  for (int i = 0; i < 4; ++i) {
    #pragma unroll
    for (int j = 0; j < 4; ++j) {
      #pragma unroll
      for (int q = 0; q < 4; ++q) {
        int rowg = brow + wm * 64 + i * 16 + g * 4 + q;
        int colg = bcol + wn * 64 + j * 16 + rr;
        size_t off = (size_t)rowg * N + colg;
        float vacc = acc[i][j][q];
        if (EPI == 0) {
          outb[off] = f2b(vacc);
        } else if (EPI == 1) {
          float nx = xres[off] + vacc;
          xres[off] = nx; outb[off] = f2b(nx);
        } else if (EPI == 2) {
          float hv = vacc + bias[colg];
          hv = hv > 0.f ? hv : 0.f;
          outb[off] = f2b(hv);
        } else {
          float nx = xres[off] + vacc + bias[colg];
          xres[off] = nx; outb[off] = f2b(nx);
        }
      }
    }
  }
}

// ---------------- MFMA flash attention (unchanged from R2) ----------------
template<int E>
__device__ __forceinline__ bf16x8 buildP(const f32x16& p) {
  uint32_t a = pkbf(p[E + 0], p[E + 1]);
  uint32_t b = pkbf(p[E + 4], p[E + 5]);
  uint32_t c = pkbf(p[E + 2], p[E + 3]);
  uint32_t d = pkbf(p[E + 6], p[E + 7]);
  asm("v_permlane32_swap_b32 %0, %1" : "+v"(a), "+v"(b));
  asm("v_permlane32_swap_b32 %0, %1" : "+v"(c), "+v"(d));
  union { uint32_t u[4]; bf16x8 v; } r;
  r.u[0] = a; r.u[1] = c; r.u[2] = b; r.u[3] = d;
  return r.v;
}

__global__ __launch_bounds__(256) void attn_kernel(const unsigned short* __restrict__ qkv,
                                                   unsigned short* __restrict__ ob) {
  __shared__ unsigned short Kl[64 * 64];
  __shared__ unsigned short Vt[64 * 64];
  const int tid = threadIdx.x;
  const int wv = tid >> 6, ln = tid & 63;
  const int lq = ln & 31, hi = ln >> 5;
  const int qt = blockIdx.x >> 8, bh = blockIdx.x & 255;
  const int b = bh >> 4, h = bh & 15;
  const int qrow = qt * 128 + wv * 32 + lq;
  const size_t rowQ = (size_t)(b * TT + qrow) * 3072 + h * 64;

  const float cs = 0.125f * 1.44269504f;
  bf16x8 qf[4];
  #pragma unroll
  for (int t = 0; t < 4; ++t) {
    uint4 u = *(const uint4*)(qkv + rowQ + t * 16 + hi * 8);
    uint32_t w[4] = {u.x, u.y, u.z, u.w};
    union { uint32_t u4[4]; bf16x8 v; } cv;
    #pragma unroll
    for (int j = 0; j < 4; ++j) cv.u4[j] = pkbf(blo(w[j]) * cs, bhi(w[j]) * cs);
    qf[t] = cv.v;
  }

  f32x16 o0 = {}, o1 = {};
  float mrun = -3.0e38f, lsum = 0.f;

  for (int kv0 = 0; kv0 < TT; kv0 += 64) {
    if (kv0) __syncthreads();
    #pragma unroll
    for (int r = 0; r < 2; ++r) {
      int ch = r * 256 + tid;
      int k = ch >> 3, cc = ch & 7;
      int sg = (k & 7) ^ (k >> 3);
      const unsigned short* gs = qkv + (size_t)(b * TT + kv0 + k) * 3072 + 1024 + h * 64 + ((cc ^ sg) << 3);
      gload16(gs, Kl + (size_t)(r * 256 + wv * 64) * 8);
    }
    {
      int cc = tid & 7, kp = tid >> 3;
      int k = kp * 2;
      const unsigned short* gv = qkv + (size_t)(b * TT + kv0 + k) * 3072 + 2048 + h * 64 + cc * 8;
      uint4 g1 = *(const uint4*)gv;
      uint4 g2 = *(const uint4*)(gv + 3072);
      uint32_t w1[4] = {g1.x, g1.y, g1.z, g1.w}, w2[4] = {g2.x, g2.y, g2.z, g2.w};
      #pragma unroll
      for (int j = 0; j < 8; ++j) {
        int d = cc * 8 + j;
        uint32_t dw = (j & 1) ? ((w1[j >> 1] >> 16) | (w2[j >> 1] & 0xFFFF0000u))
                              : ((w1[j >> 1] & 0xFFFFu) | (w2[j >> 1] << 16));
        int sg = (d & 7) ^ (d >> 3);
        *(uint32_t*)(Vt + d * 64 + (k ^ (sg << 3))) = dw;
      }
    }
    __syncthreads();

    f32x16 s0 = {}, s1 = {};
    #pragma unroll
    for (int t = 0; t < 4; ++t) {
      int r0 = lq, r1 = 32 + lq;
      bf16x8 a0 = *(const bf16x8*)(Kl + r0 * 64 + ((((t << 1) | hi) ^ ((r0 & 7) ^ (r0 >> 3))) << 3));
      bf16x8 a1 = *(const bf16x8*)(Kl + r1 * 64 + ((((t << 1) | hi) ^ ((r1 & 7) ^ (r1 >> 3))) << 3));
      s0 = __builtin_amdgcn_mfma_f32_32x32x16_bf16(a0, qf[t], s0, 0, 0, 0);
      s1 = __builtin_amdgcn_mfma_f32_32x32x16_bf16(a1, qf[t], s1, 0, 0, 0);
    }

    float mx = s0[0];
    #pragma unroll
    for (int r = 1; r < 16; ++r) mx = fmaxf(mx, s0[r]);
    #pragma unroll
    for (int r = 0; r < 16; ++r) mx = fmaxf(mx, s1[r]);
    mx = fmaxf(mx, __shfl_xor(mx, 32));
    float mnew = fmaxf(mrun, mx);
    float cf = ex2(mrun - mnew);
    mrun = mnew;
    lsum *= cf;
    #pragma unroll
    for (int r = 0; r < 16; ++r) { o0[r] *= cf; o1[r] *= cf; }
    #pragma unroll
    for (int r = 0; r < 16; ++r) {
      s0[r] = ex2(s0[r] - mnew);
      s1[r] = ex2(s1[r] - mnew);
      lsum += s0[r] + s1[r];
    }

    bf16x8 pf0 = buildP<0>(s0);
    bf16x8 pf1 = buildP<8>(s0);
    bf16x8 pf2 = buildP<0>(s1);
    bf16x8 pf3 = buildP<8>(s1);

    #pragma unroll
    for (int t = 0; t < 4; ++t) {
      bf16x8 pf = (t == 0) ? pf0 : (t == 1) ? pf1 : (t == 2) ? pf2 : pf3;
      int d0 = lq, d1 = 32 + lq;
      bf16x8 v0 = *(const bf16x8*)(Vt + d0 * 64 + ((((t << 1) | hi) ^ ((d0 & 7) ^ (d0 >> 3))) << 3));
      bf16x8 v1 = *(const bf16x8*)(Vt + d1 * 64 + ((((t << 1) | hi) ^ ((d1 & 7) ^ (d1 >> 3))) << 3));
      o0 = __builtin_amdgcn_mfma_f32_32x32x16_bf16(v0, pf, o0, 0, 0, 0);
      o1 = __builtin_amdgcn_mfma_f32_32x32x16_bf16(v1, pf, o1, 0, 0, 0);
    }
  }

  lsum += __shfl_xor(lsum, 32);
  float inv = 1.f / lsum;
  size_t orow = (size_t)(b * TT + qrow) * CC + h * 64;
  #pragma unroll
  for (int md = 0; md < 2; ++md) {
    #pragma unroll
    for (int rq = 0; rq < 4; ++rq) {
      int d0 = md * 32 + rq * 8 + hi * 4;
      float e0 = (md ? o1[rq * 4 + 0] : o0[rq * 4 + 0]) * inv;
      float e1 = (md ? o1[rq * 4 + 1] : o0[rq * 4 + 1]) * inv;
      float e2 = (md ? o1[rq * 4 + 2] : o0[rq * 4 + 2]) * inv;
      float e3 = (md ? o1[rq * 4 + 3] : o0[rq * 4 + 3]) * inv;
      uint2 st; st.x = pkbf(e0, e1); st.y = pkbf(e2, e3);
      *(uint2*)(ob + orow + d0) = st;
    }
  }
}

// ---------------- final: out[b,c] = sum_t x[b,t,c] * I[b,t] ----------------
__global__ __launch_bounds__(256) void final_kernel(const float* __restrict__ x,
                                                    const float* __restrict__ I,
                                                    float* __restrict__ out) {
  int b = blockIdx.x >> 2;
  int c = ((blockIdx.x & 3) << 8) + threadIdx.x;
  float acc = 0.f;
  const float* xp = x + (size_t)b * TT * CC + c;
  const float* Ip = I + (size_t)b * TT;
  for (int t = 0; t < TT; ++t) acc = fmaf(xp[(size_t)t * CC], Ip[t], acc);
  out[b * CC + c] = acc;
}

extern "C" void kernel_launch(void* const* d_in, const int* in_sizes, int n_in,
                              void* d_out, int out_size, void* d_ws, size_t ws_size,
                              hipStream_t stream) {
  const int*   X      = (const int*)d_in[0];
  const float* I      = (const float*)d_in[1];
  const int*   S      = (const int*)d_in[2];
  const float* emb    = (const float*)d_in[3];
  const float* pos    = (const float*)d_in[4];
  const float* qkv_w  = (const float*)d_in[5];
  const float* out_w  = (const float*)d_in[6];
  const float* ffn_w1 = (const float*)d_in[7];
  const float* ffn_b1 = (const float*)d_in[8];
  const float* ffn_w2 = (const float*)d_in[9];
  const float* ffn_b2 = (const float*)d_in[10];
  float* out = (float*)d_out;

  char* ws = (char*)d_ws;
  size_t off = 0;
  auto walloc = [&](size_t bytes) { char* p = ws + off; off += (bytes + 255) & ~(size_t)255; return p; };
  unsigned short* wqkv = (unsigned short*)walloc((size_t)LAYERS * 3 * CC * CC * 2);
  unsigned short* wo   = (unsigned short*)walloc((size_t)LAYERS * CC * CC * 2);
  unsigned short* w1   = (unsigned short*)walloc((size_t)LAYERS * CC * CC * 2);
  unsigned short* w2   = (unsigned short*)walloc((size_t)LAYERS * CC * CC * 2);
  float*          x    = (float*)walloc((size_t)MM * CC * 4);
  unsigned short* xb   = (unsigned short*)walloc((size_t)MM * CC * 2);
  unsigned short* qkvb = (unsigned short*)walloc((size_t)MM * 3 * CC * 2);
  unsigned short* obuf = (unsigned short*)walloc((size_t)MM * CC * 2);
  unsigned short* hbuf = (unsigned short*)walloc((size_t)MM * CC * 2);
  if (off > ws_size) return;

  int n4;
  n4 = LAYERS * 3 * CC * CC / 4; cvt_kernel<<<(n4 + 255) / 256, 256, 0, stream>>>(qkv_w, wqkv, n4);
  n4 = LAYERS * CC * CC / 4;     cvt_kernel<<<(n4 + 255) / 256, 256, 0, stream>>>(out_w, wo, n4);
  n4 = LAYERS * CC * CC / 4;     cvt_kernel<<<(n4 + 255) / 256, 256, 0, stream>>>(ffn_w1, w1, n4);
  n4 = LAYERS * CC * CC / 4;     cvt_kernel<<<(n4 + 255) / 256, 256, 0, stream>>>(ffn_w2, w2, n4);

  embed_kernel<<<MM, 256, 0, stream>>>(X, S, emb, pos, x, xb);

  const size_t ldsB = 144 * 1024;
  for (int l = 0; l < LAYERS; ++l) {
    gemm4_kernel<0><<<(MM / 256) * (3 * CC / 128), 512, ldsB, stream>>>(
        xb, wqkv + (size_t)l * 3 * CC * CC, nullptr, qkvb, nullptr, 3 * CC, 3 * CC / 128);
    attn_kernel<<<4 * 256, 256, 0, stream>>>(qkvb, obuf);
    gemm4_kernel<1><<<(MM / 256) * (CC / 128), 512, ldsB, stream>>>(
        obuf, wo + (size_t)l * CC * CC, x, xb, nullptr, CC, CC / 128);
    gemm4_kernel<2><<<(MM / 256) * (CC / 128), 512, ldsB, stream>>>(
        xb, w1 + (size_t)l * CC * CC, nullptr, hbuf, ffn_b1 + l * CC, CC, CC / 128);
    gemm4_kernel<3><<<(MM / 256) * (CC / 128), 512, ldsB, stream>>>(
        hbuf, w2 + (size_t)l * CC * CC, x, xb, ffn_b2 + l * CC, CC, CC / 128);
  }

  final_kernel<<<BB * 4, 256, 0, stream>>>(x, I, out);
}

// Round 7
// 791.444 us; speedup vs baseline: 1.4315x; 1.0408x over previous
//
#include <hip/hip_runtime.h>
#include <stdint.h>

#define LAYERS 4
#define BB 16
#define TT 512
#define CC 1024
#define HH 16
#define DD 64
#define VV 32000
#define MM (BB*TT)   // 8192 rows

typedef __attribute__((ext_vector_type(8))) short bf16x8;
typedef __attribute__((ext_vector_type(4))) float f32x4;
typedef __attribute__((ext_vector_type(16))) float f32x16;

__device__ __forceinline__ unsigned short f2b(float f) {
  union { float f; unsigned int u; } v; v.f = f;
  unsigned int r = v.u + 0x7FFFu + ((v.u >> 16) & 1u);
  return (unsigned short)(r >> 16);
}
__device__ __forceinline__ float blo(unsigned int u) {
  union { unsigned int x; float f; } v; v.x = u << 16; return v.f;
}
__device__ __forceinline__ float bhi(unsigned int u) {
  union { unsigned int x; float f; } v; v.x = u & 0xFFFF0000u; return v.f;
}
__device__ __forceinline__ uint32_t pkbf(float lo, float hi) {
  uint32_t d; asm("v_cvt_pk_bf16_f32 %0, %1, %2" : "=v"(d) : "v"(lo), "v"(hi)); return d;
}
__device__ __forceinline__ float ex2(float x) {
  float r; asm("v_exp_f32 %0, %1" : "=v"(r) : "v"(x)); return r;
}
__device__ __forceinline__ void gload16(const unsigned short* g, const unsigned short* lds) {
  __builtin_amdgcn_global_load_lds((const __attribute__((address_space(1))) void*)g,
                                   (__attribute__((address_space(3))) void*)lds, 16, 0, 0);
}

// ---------------- weight fp32 -> bf16 ----------------
__global__ __launch_bounds__(256) void cvt_kernel(const float* __restrict__ src,
                                                  unsigned short* __restrict__ dst, int n4) {
  int i = blockIdx.x * 256 + threadIdx.x;
  if (i >= n4) return;
  float4 v = ((const float4*)src)[i];
  ushort4 o; o.x = f2b(v.x); o.y = f2b(v.y); o.z = f2b(v.z); o.w = f2b(v.w);
  ((ushort4*)dst)[i] = o;
}

// ---------------- embedding: x = emb[Xm] + pos ----------------
__global__ __launch_bounds__(256) void embed_kernel(const int* __restrict__ X, const int* __restrict__ S,
    const float* __restrict__ emb, const float* __restrict__ pos,
    float* __restrict__ x, unsigned short* __restrict__ xb) {
  int bt = blockIdx.x; int tid = threadIdx.x;
  int t = bt & (TT - 1);
  int tok = S[bt] ? X[bt] : VV;
  float4 e = ((const float4*)(emb + (size_t)tok * CC))[tid];
  float4 p = ((const float4*)(pos + (size_t)t * CC))[tid];
  float4 r; r.x = e.x + p.x; r.y = e.y + p.y; r.z = e.z + p.z; r.w = e.w + p.w;
  ((float4*)(x + (size_t)bt * CC))[tid] = r;
  ushort4 ub; ub.x = f2b(r.x); ub.y = f2b(r.y); ub.z = f2b(r.z); ub.w = f2b(r.w);
  ((ushort4*)(xb + (size_t)bt * CC))[tid] = ub;
}

// ---------------- GEMM v5: R6 geometry + 2-phase/K-tile interleave (T3) ----------------
// 256x128 tile, 8 waves (4M x 2N), per-wave 64x64, K=1024 (NT=16).
// LDS 144KB: 3 buffers x (A[256][64]+B[128][64]) bf16, chunk-XOR swizzle (0 conflicts).
// Phase(kk): {8 ds_read_b128 || stage-half issue -> barrier -> 16 MFMA -> barrier}.
// Gates (per-wave counts, 6 loads/tile, split 4A+2B): steady vmcnt(6) at end of ph1
// (tile t+1 landed, t+2 in flight); t=14 vmcnt(0); never drains mid-pipeline.
template<int EPI>
__global__ __launch_bounds__(512, 1) void gemm5_kernel(
    const unsigned short* __restrict__ A,   // M x 1024 bf16
    const unsigned short* __restrict__ W,   // N x 1024 bf16
    float* __restrict__ xres,
    unsigned short* __restrict__ outb,
    const float* __restrict__ bias,
    int N, int nbx) {
  extern __shared__ unsigned short lds[];   // 3 x 24576 shorts
  const int K = 1024;
  const int tid = threadIdx.x;
  const int wv = tid >> 6, ln = tid & 63;
  const int g = ln >> 4, rr = ln & 15;
  const int wm = wv >> 1, wn = wv & 1;

  const int nwg = gridDim.x;
  const int bid = blockIdx.x;
  const int swz = (bid & 7) * (nwg >> 3) + (bid >> 3);
  const int by = swz / nbx, bx = swz - by * nbx;   // bx fast -> A rows L2-resident per XCD
  const int brow = by * 256, bcol = bx * 128;

  // staging source pointers (chunk column pre-XORed by row&7; G21 both-sides swizzle)
  const unsigned short* asrc[4];
  const unsigned short* bsrc[2];
  #pragma unroll
  for (int rd = 0; rd < 4; ++rd) {
    int ch = rd * 512 + tid;
    int row = ch >> 3, c = (ch & 7) ^ (row & 7);
    asrc[rd] = A + (size_t)(brow + row) * K + c * 8;
  }
  #pragma unroll
  for (int rd = 0; rd < 2; ++rd) {
    int ch = rd * 512 + tid;
    int row = ch >> 3, c = (ch & 7) ^ (row & 7);
    bsrc[rd] = W + (size_t)(bcol + row) * K + c * 8;
  }

  auto stageA = [&](int tile, int buf) {
    unsigned short* Ad = lds + buf * 24576 + wv * 512;
    int ko = tile * 64;
    #pragma unroll
    for (int rd = 0; rd < 4; ++rd) gload16(asrc[rd] + ko, Ad + rd * 4096);
  };
  auto stageB = [&](int tile, int buf) {
    unsigned short* Bd = lds + buf * 24576 + 16384 + wv * 512;
    int ko = tile * 64;
    #pragma unroll
    for (int rd = 0; rd < 2; ++rd) gload16(bsrc[rd] + ko, Bd + rd * 4096);
  };

  f32x4 acc[4][4];
  #pragma unroll
  for (int i = 0; i < 4; ++i)
    #pragma unroll
    for (int j = 0; j < 4; ++j)
      acc[i][j] = (f32x4){0.f, 0.f, 0.f, 0.f};

  stageA(0, 0); stageB(0, 0);
  stageA(1, 1); stageB(1, 1);
  asm volatile("s_waitcnt vmcnt(6)" ::: "memory");   // tile 0 landed (own 6 loads)
  __builtin_amdgcn_s_barrier();

  int bufc = 0;
  for (int t = 0; t < 16; ++t) {
    int bufn = bufc + 2; if (bufn >= 3) bufn -= 3;
    const unsigned short* Ab = lds + bufc * 24576;
    const unsigned short* Bb = Ab + 16384;

    // ---- phase 0 (kk = 0) ----
    {
      bf16x8 av[4], bv[4];
      const int chx = ((0 * 4 + g) ^ (rr & 7)) << 3;
      #pragma unroll
      for (int i = 0; i < 4; ++i)
        av[i] = *(const bf16x8*)(Ab + (wm * 64 + i * 16 + rr) * 64 + chx);
      #pragma unroll
      for (int j = 0; j < 4; ++j)
        bv[j] = *(const bf16x8*)(Bb + (wn * 64 + j * 16 + rr) * 64 + chx);
      if (t < 14) stageA(t + 2, bufn);
      __builtin_amdgcn_sched_barrier(0);
      __builtin_amdgcn_s_barrier();
      __builtin_amdgcn_s_setprio(1);
      #pragma unroll
      for (int i = 0; i < 4; ++i)
        #pragma unroll
        for (int j = 0; j < 4; ++j)
          acc[i][j] = __builtin_amdgcn_mfma_f32_16x16x32_bf16(av[i], bv[j], acc[i][j], 0, 0, 0);
      __builtin_amdgcn_s_setprio(0);
      __builtin_amdgcn_sched_barrier(0);
      __builtin_amdgcn_s_barrier();
    }

    // ---- phase 1 (kk = 1) ----
    {
      bf16x8 av[4], bv[4];
      const int chx = ((1 * 4 + g) ^ (rr & 7)) << 3;
      #pragma unroll
      for (int i = 0; i < 4; ++i)
        av[i] = *(const bf16x8*)(Ab + (wm * 64 + i * 16 + rr) * 64 + chx);
      #pragma unroll
      for (int j = 0; j < 4; ++j)
        bv[j] = *(const bf16x8*)(Bb + (wn * 64 + j * 16 + rr) * 64 + chx);
      if (t < 14) stageB(t + 2, bufn);
      __builtin_amdgcn_sched_barrier(0);
      __builtin_amdgcn_s_barrier();
      __builtin_amdgcn_s_setprio(1);
      #pragma unroll
      for (int i = 0; i < 4; ++i)
        #pragma unroll
        for (int j = 0; j < 4; ++j)
          acc[i][j] = __builtin_amdgcn_mfma_f32_16x16x32_bf16(av[i], bv[j], acc[i][j], 0, 0, 0);
      __builtin_amdgcn_s_setprio(0);
      // gate: t+1 fully landed (<=6 outstanding = only t+2 in flight)
      if (t < 14) { asm volatile("s_waitcnt vmcnt(6)" ::: "memory"); }
      else if (t == 14) { asm volatile("s_waitcnt vmcnt(0)" ::: "memory"); }
      __builtin_amdgcn_sched_barrier(0);
      __builtin_amdgcn_s_barrier();
    }
    bufc += 1; if (bufc == 3) bufc = 0;
  }

  // epilogue: D row = (ln>>4)*4 + q, col = ln&15
  #pragma unroll
  for (int i = 0; i < 4; ++i) {
    #pragma unroll
    for (int j = 0; j < 4; ++j) {
      #pragma unroll
      for (int q = 0; q < 4; ++q) {
        int rowg = brow + wm * 64 + i * 16 + g * 4 + q;
        int colg = bcol + wn * 64 + j * 16 + rr;
        size_t off = (size_t)rowg * N + colg;
        float vacc = acc[i][j][q];
        if (EPI == 0) {
          outb[off] = f2b(vacc);
        } else if (EPI == 1) {
          float nx = xres[off] + vacc;
          xres[off] = nx; outb[off] = f2b(nx);
        } else if (EPI == 2) {
          float hv = vacc + bias[colg];
          hv = hv > 0.f ? hv : 0.f;
          outb[off] = f2b(hv);
        } else {
          float nx = xres[off] + vacc + bias[colg];
          xres[off] = nx; outb[off] = f2b(nx);
        }
      }
    }
  }
}

// ---------------- MFMA flash attention (unchanged from R2) ----------------
template<int E>
__device__ __forceinline__ bf16x8 buildP(const f32x16& p) {
  uint32_t a = pkbf(p[E + 0], p[E + 1]);
  uint32_t b = pkbf(p[E + 4], p[E + 5]);
  uint32_t c = pkbf(p[E + 2], p[E + 3]);
  uint32_t d = pkbf(p[E + 6], p[E + 7]);
  asm("v_permlane32_swap_b32 %0, %1" : "+v"(a), "+v"(b));
  asm("v_permlane32_swap_b32 %0, %1" : "+v"(c), "+v"(d));
  union { uint32_t u[4]; bf16x8 v; } r;
  r.u[0] = a; r.u[1] = c; r.u[2] = b; r.u[3] = d;
  return r.v;
}

__global__ __launch_bounds__(256) void attn_kernel(const unsigned short* __restrict__ qkv,
                                                   unsigned short* __restrict__ ob) {
  __shared__ unsigned short Kl[64 * 64];
  __shared__ unsigned short Vt[64 * 64];
  const int tid = threadIdx.x;
  const int wv = tid >> 6, ln = tid & 63;
  const int lq = ln & 31, hi = ln >> 5;
  const int qt = blockIdx.x >> 8, bh = blockIdx.x & 255;
  const int b = bh >> 4, h = bh & 15;
  const int qrow = qt * 128 + wv * 32 + lq;
  const size_t rowQ = (size_t)(b * TT + qrow) * 3072 + h * 64;

  const float cs = 0.125f * 1.44269504f;
  bf16x8 qf[4];
  #pragma unroll
  for (int t = 0; t < 4; ++t) {
    uint4 u = *(const uint4*)(qkv + rowQ + t * 16 + hi * 8);
    uint32_t w[4] = {u.x, u.y, u.z, u.w};
    union { uint32_t u4[4]; bf16x8 v; } cv;
    #pragma unroll
    for (int j = 0; j < 4; ++j) cv.u4[j] = pkbf(blo(w[j]) * cs, bhi(w[j]) * cs);
    qf[t] = cv.v;
  }

  f32x16 o0 = {}, o1 = {};
  float mrun = -3.0e38f, lsum = 0.f;

  for (int kv0 = 0; kv0 < TT; kv0 += 64) {
    if (kv0) __syncthreads();
    #pragma unroll
    for (int r = 0; r < 2; ++r) {
      int ch = r * 256 + tid;
      int k = ch >> 3, cc = ch & 7;
      int sg = (k & 7) ^ (k >> 3);
      const unsigned short* gs = qkv + (size_t)(b * TT + kv0 + k) * 3072 + 1024 + h * 64 + ((cc ^ sg) << 3);
      gload16(gs, Kl + (size_t)(r * 256 + wv * 64) * 8);
    }
    {
      int cc = tid & 7, kp = tid >> 3;
      int k = kp * 2;
      const unsigned short* gv = qkv + (size_t)(b * TT + kv0 + k) * 3072 + 2048 + h * 64 + cc * 8;
      uint4 g1 = *(const uint4*)gv;
      uint4 g2 = *(const uint4*)(gv + 3072);
      uint32_t w1[4] = {g1.x, g1.y, g1.z, g1.w}, w2[4] = {g2.x, g2.y, g2.z, g2.w};
      #pragma unroll
      for (int j = 0; j < 8; ++j) {
        int d = cc * 8 + j;
        uint32_t dw = (j & 1) ? ((w1[j >> 1] >> 16) | (w2[j >> 1] & 0xFFFF0000u))
                              : ((w1[j >> 1] & 0xFFFFu) | (w2[j >> 1] << 16));
        int sg = (d & 7) ^ (d >> 3);
        *(uint32_t*)(Vt + d * 64 + (k ^ (sg << 3))) = dw;
      }
    }
    __syncthreads();

    f32x16 s0 = {}, s1 = {};
    #pragma unroll
    for (int t = 0; t < 4; ++t) {
      int r0 = lq, r1 = 32 + lq;
      bf16x8 a0 = *(const bf16x8*)(Kl + r0 * 64 + ((((t << 1) | hi) ^ ((r0 & 7) ^ (r0 >> 3))) << 3));
      bf16x8 a1 = *(const bf16x8*)(Kl + r1 * 64 + ((((t << 1) | hi) ^ ((r1 & 7) ^ (r1 >> 3))) << 3));
      s0 = __builtin_amdgcn_mfma_f32_32x32x16_bf16(a0, qf[t], s0, 0, 0, 0);
      s1 = __builtin_amdgcn_mfma_f32_32x32x16_bf16(a1, qf[t], s1, 0, 0, 0);
    }

    float mx = s0[0];
    #pragma unroll
    for (int r = 1; r < 16; ++r) mx = fmaxf(mx, s0[r]);
    #pragma unroll
    for (int r = 0; r < 16; ++r) mx = fmaxf(mx, s1[r]);
    mx = fmaxf(mx, __shfl_xor(mx, 32));
    float mnew = fmaxf(mrun, mx);
    float cf = ex2(mrun - mnew);
    mrun = mnew;
    lsum *= cf;
    #pragma unroll
    for (int r = 0; r < 16; ++r) { o0[r] *= cf; o1[r] *= cf; }
    #pragma unroll
    for (int r = 0; r < 16; ++r) {
      s0[r] = ex2(s0[r] - mnew);
      s1[r] = ex2(s1[r] - mnew);
      lsum += s0[r] + s1[r];
    }

    bf16x8 pf0 = buildP<0>(s0);
    bf16x8 pf1 = buildP<8>(s0);
    bf16x8 pf2 = buildP<0>(s1);
    bf16x8 pf3 = buildP<8>(s1);

    #pragma unroll
    for (int t = 0; t < 4; ++t) {
      bf16x8 pf = (t == 0) ? pf0 : (t == 1) ? pf1 : (t == 2) ? pf2 : pf3;
      int d0 = lq, d1 = 32 + lq;
      bf16x8 v0 = *(const bf16x8*)(Vt + d0 * 64 + ((((t << 1) | hi) ^ ((d0 & 7) ^ (d0 >> 3))) << 3));
      bf16x8 v1 = *(const bf16x8*)(Vt + d1 * 64 + ((((t << 1) | hi) ^ ((d1 & 7) ^ (d1 >> 3))) << 3));
      o0 = __builtin_amdgcn_mfma_f32_32x32x16_bf16(v0, pf, o0, 0, 0, 0);
      o1 = __builtin_amdgcn_mfma_f32_32x32x16_bf16(v1, pf, o1, 0, 0, 0);
    }
  }

  lsum += __shfl_xor(lsum, 32);
  float inv = 1.f / lsum;
  size_t orow = (size_t)(b * TT + qrow) * CC + h * 64;
  #pragma unroll
  for (int md = 0; md < 2; ++md) {
    #pragma unroll
    for (int rq = 0; rq < 4; ++rq) {
      int d0 = md * 32 + rq * 8 + hi * 4;
      float e0 = (md ? o1[rq * 4 + 0] : o0[rq * 4 + 0]) * inv;
      float e1 = (md ? o1[rq * 4 + 1] : o0[rq * 4 + 1]) * inv;
      float e2 = (md ? o1[rq * 4 + 2] : o0[rq * 4 + 2]) * inv;
      float e3 = (md ? o1[rq * 4 + 3] : o0[rq * 4 + 3]) * inv;
      uint2 st; st.x = pkbf(e0, e1); st.y = pkbf(e2, e3);
      *(uint2*)(ob + orow + d0) = st;
    }
  }
}

// ---------------- final: out[b,c] = sum_t x[b,t,c] * I[b,t] ----------------
__global__ __launch_bounds__(256) void final_kernel(const float* __restrict__ x,
                                                    const float* __restrict__ I,
                                                    float* __restrict__ out) {
  int b = blockIdx.x >> 2;
  int c = ((blockIdx.x & 3) << 8) + threadIdx.x;
  float acc = 0.f;
  const float* xp = x + (size_t)b * TT * CC + c;
  const float* Ip = I + (size_t)b * TT;
  for (int t = 0; t < TT; ++t) acc = fmaf(xp[(size_t)t * CC], Ip[t], acc);
  out[b * CC + c] = acc;
}

extern "C" void kernel_launch(void* const* d_in, const int* in_sizes, int n_in,
                              void* d_out, int out_size, void* d_ws, size_t ws_size,
                              hipStream_t stream) {
  const int*   X      = (const int*)d_in[0];
  const float* I      = (const float*)d_in[1];
  const int*   S      = (const int*)d_in[2];
  const float* emb    = (const float*)d_in[3];
  const float* pos    = (const float*)d_in[4];
  const float* qkv_w  = (const float*)d_in[5];
  const float* out_w  = (const float*)d_in[6];
  const float* ffn_w1 = (const float*)d_in[7];
  const float* ffn_b1 = (const float*)d_in[8];
  const float* ffn_w2 = (const float*)d_in[9];
  const float* ffn_b2 = (const float*)d_in[10];
  float* out = (float*)d_out;

  char* ws = (char*)d_ws;
  size_t off = 0;
  auto walloc = [&](size_t bytes) { char* p = ws + off; off += (bytes + 255) & ~(size_t)255; return p; };
  unsigned short* wqkv = (unsigned short*)walloc((size_t)LAYERS * 3 * CC * CC * 2);
  unsigned short* wo   = (unsigned short*)walloc((size_t)LAYERS * CC * CC * 2);
  unsigned short* w1   = (unsigned short*)walloc((size_t)LAYERS * CC * CC * 2);
  unsigned short* w2   = (unsigned short*)walloc((size_t)LAYERS * CC * CC * 2);
  float*          x    = (float*)walloc((size_t)MM * CC * 4);
  unsigned short* xb   = (unsigned short*)walloc((size_t)MM * CC * 2);
  unsigned short* qkvb = (unsigned short*)walloc((size_t)MM * 3 * CC * 2);
  unsigned short* obuf = (unsigned short*)walloc((size_t)MM * CC * 2);
  unsigned short* hbuf = (unsigned short*)walloc((size_t)MM * CC * 2);
  if (off > ws_size) return;

  int n4;
  n4 = LAYERS * 3 * CC * CC / 4; cvt_kernel<<<(n4 + 255) / 256, 256, 0, stream>>>(qkv_w, wqkv, n4);
  n4 = LAYERS * CC * CC / 4;     cvt_kernel<<<(n4 + 255) / 256, 256, 0, stream>>>(out_w, wo, n4);
  n4 = LAYERS * CC * CC / 4;     cvt_kernel<<<(n4 + 255) / 256, 256, 0, stream>>>(ffn_w1, w1, n4);
  n4 = LAYERS * CC * CC / 4;     cvt_kernel<<<(n4 + 255) / 256, 256, 0, stream>>>(ffn_w2, w2, n4);

  embed_kernel<<<MM, 256, 0, stream>>>(X, S, emb, pos, x, xb);

  const size_t ldsB = 144 * 1024;
  for (int l = 0; l < LAYERS; ++l) {
    gemm5_kernel<0><<<(MM / 256) * (3 * CC / 128), 512, ldsB, stream>>>(
        xb, wqkv + (size_t)l * 3 * CC * CC, nullptr, qkvb, nullptr, 3 * CC, 3 * CC / 128);
    attn_kernel<<<4 * 256, 256, 0, stream>>>(qkvb, obuf);
    gemm5_kernel<1><<<(MM / 256) * (CC / 128), 512, ldsB, stream>>>(
        obuf, wo + (size_t)l * CC * CC, x, xb, nullptr, CC, CC / 128);
    gemm5_kernel<2><<<(MM / 256) * (CC / 128), 512, ldsB, stream>>>(
        xb, w1 + (size_t)l * CC * CC, nullptr, hbuf, ffn_b1 + l * CC, CC, CC / 128);
    gemm5_kernel<3><<<(MM / 256) * (CC / 128), 512, ldsB, stream>>>(
        hbuf, w2 + (size_t)l * CC * CC, x, xb, ffn_b2 + l * CC, CC, CC / 128);
  }

  final_kernel<<<BB * 4, 256, 0, stream>>>(x, I, out);
}